// Round 3
// baseline (588.529 us; speedup 1.0000x reference)
//
#include <hip/hip_runtime.h>

#define N_NODES 8192
#define N_EDGES 65536
#define FEAT    136
#define WNUM    3392

typedef __attribute__((ext_vector_type(4))) short s16x4;
typedef __attribute__((ext_vector_type(8))) short s16x8;
typedef __attribute__((ext_vector_type(4))) float f32x4;

__device__ __forceinline__ float b2f(unsigned short h) {
    union { unsigned int u; float f; } v; v.u = ((unsigned int)h) << 16; return v.f;
}
__device__ __forceinline__ unsigned short f2b(float f) {
    union { float f; unsigned int u; } v; v.f = f;
    unsigned int u = v.u;
    unsigned int r = (u + 0x7FFFu + ((u >> 16) & 1u)) >> 16;
    return (unsigned short)r;
}

// ---- prep: W2 (64x3392 f32) -> w2t (3392x64 bf16); W1 (64x64 f32) -> w1t (64x64 bf16 T) ----
__global__ void transpose_kernel(const float* __restrict__ w2,
                                 const float* __restrict__ w1,
                                 unsigned short* __restrict__ w2t,
                                 unsigned short* __restrict__ w1t) {
    __shared__ unsigned short tl[64 * 65];
    const int b = blockIdx.x, tid = threadIdx.x;
    if (b < 53) {
        const int c0 = b * 64;
        for (int idx = tid; idx < 4096; idx += 256) {
            int k = idx >> 6, c = idx & 63;
            tl[c * 65 + k] = f2b(w2[k * WNUM + c0 + c]);   // coalesced read over c
        }
        __syncthreads();
        for (int idx = tid; idx < 4096; idx += 256) {
            int c = idx >> 6, k = idx & 63;
            w2t[(c0 + c) * 64 + k] = tl[c * 65 + k];       // coalesced write over k
        }
    } else {
        for (int idx = tid; idx < 4096; idx += 256) {
            int k = idx >> 6, j = idx & 63;
            tl[j * 65 + k] = f2b(w1[k * 64 + j]);
        }
        __syncthreads();
        for (int idx = tid; idx < 4096; idx += 256) {
            int j = idx >> 6, k = idx & 63;
            w1t[j * 64 + k] = tl[j * 65 + k];
        }
    }
}

// ---------------- fused main kernel: 64 edges per block ----------------
__global__ __launch_bounds__(256, 2)
void tpconv_main(const float* __restrict__ node_attr,
                 const int* __restrict__ edge_index,
                 const float* __restrict__ edge_attr,
                 const float* __restrict__ edge_sh,
                 const unsigned short* __restrict__ w1t,
                 const float* __restrict__ b1,
                 const unsigned short* __restrict__ w2t,
                 const float* __restrict__ b2,
                 float* __restrict__ acc_g,
                 float* __restrict__ cnt_g) {
    __shared__ unsigned short h_lds[64 * 72];     // h tile bf16, [edge][k]
    __shared__ unsigned short o_lds[64 * 388];    // o factors bf16 (scaled), [edge][384]
    __shared__ unsigned short xw_lds[9216];       // union: x gather bf16 (64*144) / W2 dbuf (2*64*72)
    __shared__ float sh_lds[64 * 4];
    __shared__ int src_lds[64];
    __shared__ int dst_lds[64];

    const int tid  = threadIdx.x;
    const int lane = tid & 63;
    const int wv   = tid >> 6;       // wave 0..3 -> 16-edge stripe
    const int n    = lane & 15;
    const int quad = lane >> 4;
    const int eb   = blockIdx.x * 64;

    // ---- step 1: indices, sh, counts ----
    if (tid < 64) {
        int s = edge_index[eb + tid];
        int d = edge_index[N_EDGES + eb + tid];
        src_lds[tid] = s;
        dst_lds[tid] = d;
        atomicAdd(&cnt_g[s], 1.0f);
        const float4 shv = *(const float4*)&edge_sh[(size_t)(eb + tid) * 4];
        sh_lds[tid * 4 + 0] = shv.x;
        sh_lds[tid * 4 + 1] = shv.y;
        sh_lds[tid * 4 + 2] = shv.z;
        sh_lds[tid * 4 + 3] = shv.w;
    }

    // ---- h phase: h = relu(ea @ W1 + b1) via MFMA, write h_lds ----
    {
        const float* ea = edge_attr + (size_t)(eb + wv * 16 + n) * 64 + quad * 8;
        s16x8 a0, a1;
#pragma unroll
        for (int j = 0; j < 8; ++j) {
            a0[j] = (short)f2b(ea[j]);        // A[m=n][k=quad*8+j]
            a1[j] = (short)f2b(ea[32 + j]);
        }
        for (int ct = 0; ct < 4; ++ct) {
            int col = ct * 16 + n;
            const unsigned short* wp = w1t + col * 64;  // B[k][n] = W1T[col][k]
            s16x8 bu0 = *(const s16x8*)&wp[quad * 8];
            s16x8 bu1 = *(const s16x8*)&wp[32 + quad * 8];
            f32x4 acc = {0.f, 0.f, 0.f, 0.f};
            acc = __builtin_amdgcn_mfma_f32_16x16x32_bf16(a0, bu0, acc, 0, 0, 0);
            acc = __builtin_amdgcn_mfma_f32_16x16x32_bf16(a1, bu1, acc, 0, 0, 0);
            float bias = b1[col];
            for (int r = 0; r < 4; ++r) {
                float hv = acc[r] + bias;
                hv = hv > 0.f ? hv : 0.f;
                // D: col=lane&15, row(edge)=quad*4+r
                h_lds[(wv * 16 + quad * 4 + r) * 72 + col] = f2b(hv);
            }
        }
    }
    __syncthreads();   // dst_lds visible

    // ---- x gather: node_attr[dst] rows (f32) -> bf16 into xw_lds ----
    for (int idx = tid; idx < 64 * 34; idx += 256) {
        int e = idx / 34, seg = idx - e * 34;             // 34 float4 segs = 136 floats
        const float4 v = *(const float4*)(node_attr + (size_t)dst_lds[e] * FEAT + seg * 4);
        s16x4 pk;
        pk[0] = (short)f2b(v.x); pk[1] = (short)f2b(v.y);
        pk[2] = (short)f2b(v.z); pk[3] = (short)f2b(v.w);
        *(s16x4*)&xw_lds[e * 144 + seg * 4] = pk;
    }
    __syncthreads();   // x, sh visible

    // ---- build o factors (block 1/sqrt(in) scales folded in) ----
    {
        const int e = tid >> 2;
        const int q = tid & 3;
        const float sh0 = sh_lds[e * 4 + 0];
        const float s1x = sh_lds[e * 4 + 1], s1y = sh_lds[e * 4 + 2], s1z = sh_lds[e * 4 + 3];
        const unsigned short* xr = &xw_lds[e * 144];
        const float inv_s3 = 0.57735026918962576f;
        const float inv_s2 = 0.70710678118654752f;
        const float sc0e = 0.14433756729740643f;   // 1/sqrt(48)
        const float sc1o = 0.125f;                 // 1/sqrt(64)
        const float sc1e = 0.15811388300841897f;   // 1/sqrt(40)
        const float sc0o = 0.20412414523193150f;   // 1/sqrt(24)
        for (int p = q * 96; p < q * 96 + 96; ++p) {
            float val;
            if (p < 48) {                                    // o0e: 48
                if (p < 32) val = b2f(xr[p]) * sh0 * sc0e;
                else {
                    int i = p - 32;
                    val = (b2f(xr[32 + i * 3]) * s1x + b2f(xr[33 + i * 3]) * s1y +
                           b2f(xr[34 + i * 3]) * s1z) * (inv_s3 * sc0e);
                }
            } else if (p < 240) {                            // o1o: (i=0..63, c) at 48+i*3+c
                int r = p - 48;
                int i = r / 3, c = r - i * 3;
                float s1c = sh_lds[e * 4 + 1 + c];
                if (i < 32) val = b2f(xr[i]) * s1c * sc1o;
                else if (i < 48) val = b2f(xr[32 + (i - 32) * 3 + c]) * sh0 * sc1o;
                else {
                    int ii = i - 48;
                    int c1 = (c == 2) ? 0 : c + 1, c2 = (c == 0) ? 2 : c - 1;
                    val = (b2f(xr[80 + ii * 3 + c1]) * sh_lds[e * 4 + 1 + c2] -
                           b2f(xr[80 + ii * 3 + c2]) * sh_lds[e * 4 + 1 + c1]) * (inv_s2 * sc1o);
                }
            } else if (p < 360) {                            // o1e: (i=0..39, c) at 240+i*3+c
                int r = p - 240;
                int i = r / 3, c = r - i * 3;
                float s1c = sh_lds[e * 4 + 1 + c];
                if (i < 16) {
                    int c1 = (c == 2) ? 0 : c + 1, c2 = (c == 0) ? 2 : c - 1;
                    val = (b2f(xr[32 + i * 3 + c1]) * sh_lds[e * 4 + 1 + c2] -
                           b2f(xr[32 + i * 3 + c2]) * sh_lds[e * 4 + 1 + c1]) * (inv_s2 * sc1e);
                } else if (i < 32) {
                    val = b2f(xr[80 + (i - 16) * 3 + c]) * sh0 * sc1e;
                } else {
                    val = b2f(xr[128 + (i - 32)]) * s1c * sc1e;
                }
            } else {                                         // o0o: 24 at 360+i
                int i = p - 360;
                if (i < 16) val = (b2f(xr[80 + i * 3]) * s1x + b2f(xr[81 + i * 3]) * s1y +
                                   b2f(xr[82 + i * 3]) * s1z) * (inv_s3 * sc0o);
                else val = b2f(xr[128 + (i - 16)]) * sh0 * sc0o;
            }
            o_lds[e * 388 + p] = f2b(val);
        }
    }
    __syncthreads();   // o_lds + h_lds ready; xw_lds now free for W2 staging

    // ---- persistent h fragments: B-operand B[k=quad*8+j][n=edge] = h[edge n][k] ----
    const unsigned short* hp = &h_lds[(wv * 16 + n) * 72];
    s16x8 h0 = *(const s16x8*)&hp[quad * 8];
    s16x8 h1 = *(const s16x8*)&hp[32 + quad * 8];

    // lane owns edge (wv*16 + n); D rows quad*4+r = W2-columns within 16-col group
    const int eo = (wv * 16 + n) * 388;

    float Y0e[4][2] = {};   // out = kk*16 + quad*4 + r
    float Y1o[4][3] = {};   // out = quad*4 + r, comp c
    float Y1e[4][3] = {};
    float Y0o[4]    = {};   // out = (quad&1)*4 + r

    unsigned short* wbuf0 = xw_lds;
    unsigned short* wbuf1 = xw_lds + 64 * 72;
    const int scol = tid >> 2, sseg = tid & 3;

    // prefetch chunk 0 of W2T into registers
    s16x8 g0, g1;
    {
        const unsigned short* gp = w2t + (size_t)scol * 64 + sseg * 16;
        g0 = *(const s16x8*)gp;
        g1 = *(const s16x8*)(gp + 8);
    }

    for (int c = 0; c < 53; ++c) {
        unsigned short* buf = (c & 1) ? wbuf1 : wbuf0;
        *(s16x8*)&buf[scol * 72 + sseg * 16]     = g0;
        *(s16x8*)&buf[scol * 72 + sseg * 16 + 8] = g1;
        __syncthreads();
        if (c < 52) {
            const unsigned short* gp = w2t + (size_t)(c + 1) * 4096 + (size_t)scol * 64 + sseg * 16;
            g0 = *(const s16x8*)gp;
            g1 = *(const s16x8*)(gp + 8);
        }
        const int c0 = c * 64;
        int blk, ibase;
        if (c0 < 1536)      { blk = 0; ibase = c0 >> 5; }
        else if (c0 < 2560) { blk = 1; ibase = (c0 - 1536) >> 4; }
        else if (c0 < 3200) { blk = 2; ibase = (c0 - 2560) >> 4; }
        else                { blk = 3; ibase = (c0 - 3200) >> 3; }

        for (int t = 0; t < 4; ++t) {
            // A-operand: A[m=n][k=quad*8+j] = W2T[c0+16t+n][k]
            const unsigned short* bp = &buf[(t * 16 + n) * 72];
            s16x8 aT0 = *(const s16x8*)&bp[quad * 8];
            s16x8 aT1 = *(const s16x8*)&bp[32 + quad * 8];
            f32x4 acc = {0.f, 0.f, 0.f, 0.f};
            acc = __builtin_amdgcn_mfma_f32_16x16x32_bf16(aT0, h0, acc, 0, 0, 0);
            acc = __builtin_amdgcn_mfma_f32_16x16x32_bf16(aT1, h1, acc, 0, 0, 0);
            // D[row=quad*4+r][col=n] = w[edge n][c0+16t+quad*4+r]  (pre-bias)
            const float4 bv = *(const float4*)(b2 + c0 + 16 * t + quad * 4);
            if (blk == 0) {                       // col = i*32 + out, out = (t&1)*16 + quad*4+r
                int i = (c0 + 16 * t) >> 5;
                float ov = b2f(o_lds[eo + i]);
                int kk = t & 1;
                Y0e[0][kk] += ov * (acc[0] + bv.x);
                Y0e[1][kk] += ov * (acc[1] + bv.y);
                Y0e[2][kk] += ov * (acc[2] + bv.z);
                Y0e[3][kk] += ov * (acc[3] + bv.w);
            } else if (blk == 1) {                // col-1536 = i*16 + out, i = ibase + t
                int ob = eo + 48 + (ibase + t) * 3;
                float o0 = b2f(o_lds[ob + 0]);
                float o1 = b2f(o_lds[ob + 1]);
                float o2 = b2f(o_lds[ob + 2]);
                for (int r = 0; r < 4; ++r) {
                    float w = acc[r] + ((const float*)&bv)[r];
                    Y1o[r][0] += o0 * w;
                    Y1o[r][1] += o1 * w;
                    Y1o[r][2] += o2 * w;
                }
            } else if (blk == 2) {                // col-2560 = i*16 + out
                int ob = eo + 240 + (ibase + t) * 3;
                float o0 = b2f(o_lds[ob + 0]);
                float o1 = b2f(o_lds[ob + 1]);
                float o2 = b2f(o_lds[ob + 2]);
                for (int r = 0; r < 4; ++r) {
                    float w = acc[r] + ((const float*)&bv)[r];
                    Y1e[r][0] += o0 * w;
                    Y1e[r][1] += o1 * w;
                    Y1e[r][2] += o2 * w;
                }
            } else {                              // col-3200 = i*8 + out, out = (quad&1)*4+r
                int i = ibase + 2 * t + (quad >> 1);
                float ov = b2f(o_lds[eo + 360 + i]);
                Y0o[0] += ov * (acc[0] + bv.x);
                Y0o[1] += ov * (acc[1] + bv.y);
                Y0o[2] += ov * (acc[2] + bv.z);
                Y0o[3] += ov * (acc[3] + bv.w);
            }
        }
    }

    // ---- scatter: atomic add into node accumulators (by src of this lane's edge) ----
    {
        float* dp = acc_g + (size_t)src_lds[wv * 16 + n] * FEAT;
        const int qr = quad * 4;
        for (int r = 0; r < 4; ++r) {
            atomicAdd(dp + qr + r,                 Y0e[r][0]);
            atomicAdd(dp + 16 + qr + r,            Y0e[r][1]);
            atomicAdd(dp + 32 + (qr + r) * 3 + 0,  Y1o[r][0]);
            atomicAdd(dp + 32 + (qr + r) * 3 + 1,  Y1o[r][1]);
            atomicAdd(dp + 32 + (qr + r) * 3 + 2,  Y1o[r][2]);
            atomicAdd(dp + 80 + (qr + r) * 3 + 0,  Y1e[r][0]);
            atomicAdd(dp + 80 + (qr + r) * 3 + 1,  Y1e[r][1]);
            atomicAdd(dp + 80 + (qr + r) * 3 + 2,  Y1e[r][2]);
            atomicAdd(dp + 128 + (quad & 1) * 4 + r, Y0o[r]);
        }
    }
}

// ---------------- finalize: mean + residual (fp32 out) ----------------
__global__ void finalize_kernel(const float* __restrict__ acc_g,
                                const float* __restrict__ cnt_g,
                                const float* __restrict__ node_attr,
                                float* __restrict__ out) {
    int idx = blockIdx.x * 256 + threadIdx.x;
    if (idx >= N_NODES * FEAT) return;
    int nn = idx / FEAT;
    float c = cnt_g[nn];
    out[idx] = acc_g[idx] / fmaxf(c, 1.0f) + node_attr[idx];
}

extern "C" void kernel_launch(void* const* d_in, const int* in_sizes, int n_in,
                              void* d_out, int out_size, void* d_ws, size_t ws_size,
                              hipStream_t stream) {
    const float* node_attr  = (const float*)d_in[0];
    const int*   edge_index = (const int*)d_in[1];
    const float* edge_attr  = (const float*)d_in[2];
    const float* edge_sh    = (const float*)d_in[3];
    const float* fc_w1      = (const float*)d_in[4];
    const float* fc_b1      = (const float*)d_in[5];
    const float* fc_w2      = (const float*)d_in[6];
    const float* fc_b2      = (const float*)d_in[7];
    float* out = (float*)d_out;

    char* ws = (char*)d_ws;
    float* acc_g = (float*)ws;                                      // 8192*136*4 = 4456448
    float* cnt_g = (float*)(ws + 4456448);                          // 8192*4     = 32768
    unsigned short* w2t = (unsigned short*)(ws + 4489216);          // 3392*64*2  = 434176
    unsigned short* w1t = (unsigned short*)(ws + 4489216 + 434176); // 64*64*2    = 8192

    hipMemsetAsync(ws, 0, 4489216, stream);  // zero acc + cnt (ws is re-poisoned every call)
    transpose_kernel<<<54, 256, 0, stream>>>(fc_w2, fc_w1, w2t, w1t);
    tpconv_main<<<1024, 256, 0, stream>>>(node_attr, edge_index, edge_attr, edge_sh,
                                          w1t, fc_b1, w2t, fc_b2, acc_g, cnt_g);
    finalize_kernel<<<(N_NODES * FEAT + 255) / 256, 256, 0, stream>>>(acc_g, cnt_g, node_attr, out);
}

// Round 4
// 209.891 us; speedup vs baseline: 2.8040x; 2.8040x over previous
//
#include <hip/hip_runtime.h>

#define N_NODES 8192
#define N_EDGES 65536
#define FEAT    136
#define WNUM    3392

typedef __attribute__((ext_vector_type(4))) short s16x4;
typedef __attribute__((ext_vector_type(8))) short s16x8;
typedef __attribute__((ext_vector_type(4))) float f32x4;

__device__ __forceinline__ float b2f(unsigned short h) {
    union { unsigned int u; float f; } v; v.u = ((unsigned int)h) << 16; return v.f;
}
__device__ __forceinline__ unsigned short f2b(float f) {
    union { float f; unsigned int u; } v; v.f = f;
    unsigned int u = v.u;
    unsigned int r = (u + 0x7FFFu + ((u >> 16) & 1u)) >> 16;
    return (unsigned short)r;
}

// total scale for W2 column `col` = 1/sqrt(fan_in) * per-i sub-factor (inv_s3/inv_s2)
__device__ __forceinline__ float wscale(int col) {
    const float inv_s3 = 0.57735026918962576f;
    const float inv_s2 = 0.70710678118654752f;
    if (col < 1536) { int i = col >> 5;          return 0.14433756729740643f * (i < 32 ? 1.f : inv_s3); }
    if (col < 2560) { int i = (col - 1536) >> 4; return 0.125f               * (i >= 48 ? inv_s2 : 1.f); }
    if (col < 3200) { int i = (col - 2560) >> 4; return 0.15811388300841897f * (i < 16 ? inv_s2 : 1.f); }
    {               int i = (col - 3200) >> 3;   return 0.20412414523193150f * (i < 16 ? inv_s3 : 1.f); }
}

// ---- prep: W2 -> w2t (3392x64 bf16, scale folded); W1 -> w1t (bf16 T); b2 -> b2s (scaled f32) ----
__global__ void transpose_kernel(const float* __restrict__ w2,
                                 const float* __restrict__ w1,
                                 const float* __restrict__ bias2,
                                 unsigned short* __restrict__ w2t,
                                 unsigned short* __restrict__ w1t,
                                 float* __restrict__ b2s) {
    __shared__ float tl[64 * 65];
    const int b = blockIdx.x, tid = threadIdx.x;
    if (b < 53) {
        const int c0 = b * 64;
        for (int idx = tid; idx < 4096; idx += 256) {
            int k = idx >> 6, c = idx & 63;
            tl[c * 65 + k] = w2[k * WNUM + c0 + c];          // coalesced read over c
        }
        __syncthreads();
        for (int idx = tid; idx < 4096; idx += 256) {
            int c = idx >> 6, k = idx & 63;
            int col = c0 + c;
            w2t[col * 64 + k] = f2b(tl[c * 65 + k] * wscale(col));
        }
        if (tid < 64) {
            int col = c0 + tid;
            b2s[col] = bias2[col] * wscale(col);
        }
    } else {
        for (int idx = tid; idx < 4096; idx += 256) {
            int k = idx >> 6, j = idx & 63;
            tl[j * 65 + k] = w1[k * 64 + j];
        }
        __syncthreads();
        for (int idx = tid; idx < 4096; idx += 256) {
            int j = idx >> 6, k = idx & 63;
            w1t[j * 64 + k] = f2b(tl[j * 65 + k]);
        }
    }
}

// ---------------- fused main kernel: 64 edges per block ----------------
__global__ __launch_bounds__(256, 3)
void tpconv_main(const float* __restrict__ node_attr,
                 const int* __restrict__ edge_index,
                 const float* __restrict__ edge_attr,
                 const float* __restrict__ edge_sh,
                 const unsigned short* __restrict__ w1t,
                 const float* __restrict__ b1,
                 const unsigned short* __restrict__ w2t,
                 const float* __restrict__ b2s,
                 float* __restrict__ acc_g,
                 float* __restrict__ cnt_g) {
    // LDS layout (48128 B total -> 3 blocks/CU):
    //  [0, 18944)      x gather, bf16, 64 rows x stride 148 (stride breaks 4-way bank alias)
    //  [18944, 37376)  W2 chunk double-buffer, 2 x 64 rows x stride 72 bf16
    //  [37376, 46592)  h tile, bf16, 64 x 72
    //  [46592, 47616)  sh, f32, 64 x 4
    //  [47616, 48128)  src, dst (int 64 each)
    //  after K-loop: [0, 36864) reused as f32 Y staging, 64 rows x 144
    __shared__ __align__(16) char smem[48128];
    unsigned short* x_lds = (unsigned short*)smem;
    unsigned short* wd0   = (unsigned short*)(smem + 18944);
    unsigned short* wd1   = (unsigned short*)(smem + 18944 + 9216);
    unsigned short* h_lds = (unsigned short*)(smem + 37376);
    float* sh_lds = (float*)(smem + 46592);
    int* src_lds  = (int*)(smem + 47616);
    int* dst_lds  = (int*)(smem + 47872);

    const int tid  = threadIdx.x;
    const int lane = tid & 63;
    const int wv   = tid >> 6;       // wave 0..3 -> 16-edge stripe
    const int n    = lane & 15;
    const int quad = lane >> 4;
    const int eb   = blockIdx.x * 64;

    // ---- indices, sh, counts ----
    if (tid < 64) {
        int s = edge_index[eb + tid];
        int d = edge_index[N_EDGES + eb + tid];
        src_lds[tid] = s;
        dst_lds[tid] = d;
        atomicAdd(&cnt_g[s], 1.0f);
        const float4 shv = *(const float4*)&edge_sh[(size_t)(eb + tid) * 4];
        sh_lds[tid * 4 + 0] = shv.x;
        sh_lds[tid * 4 + 1] = shv.y;
        sh_lds[tid * 4 + 2] = shv.z;
        sh_lds[tid * 4 + 3] = shv.w;
    }

    // ---- h = relu(ea @ W1 + b1) via MFMA -> h_lds ----
    {
        const float* ea = edge_attr + (size_t)(eb + wv * 16 + n) * 64 + quad * 8;
        s16x8 a0, a1;
#pragma unroll
        for (int j = 0; j < 8; ++j) {
            a0[j] = (short)f2b(ea[j]);        // A[m=n][k=quad*8+j]
            a1[j] = (short)f2b(ea[32 + j]);
        }
        for (int ct = 0; ct < 4; ++ct) {
            int col = ct * 16 + n;
            const unsigned short* wp = w1t + col * 64;
            s16x8 bu0 = *(const s16x8*)&wp[quad * 8];
            s16x8 bu1 = *(const s16x8*)&wp[32 + quad * 8];
            f32x4 acc = {0.f, 0.f, 0.f, 0.f};
            acc = __builtin_amdgcn_mfma_f32_16x16x32_bf16(a0, bu0, acc, 0, 0, 0);
            acc = __builtin_amdgcn_mfma_f32_16x16x32_bf16(a1, bu1, acc, 0, 0, 0);
            float bias = b1[col];
            for (int r = 0; r < 4; ++r) {
                float hv = acc[r] + bias;
                hv = hv > 0.f ? hv : 0.f;
                h_lds[(wv * 16 + quad * 4 + r) * 72 + col] = f2b(hv);  // D: col=lane&15, row=quad*4+r
            }
        }
    }
    __syncthreads();   // dst_lds + h visible

    // ---- x gather: node_attr[dst] (f32) -> bf16, stride 148 ----
    for (int idx = tid; idx < 64 * 34; idx += 256) {
        int e = idx / 34, seg = idx - e * 34;
        const float4 v = *(const float4*)(node_attr + (size_t)dst_lds[e] * FEAT + seg * 4);
        s16x4 pk;
        pk[0] = (short)f2b(v.x); pk[1] = (short)f2b(v.y);
        pk[2] = (short)f2b(v.z); pk[3] = (short)f2b(v.w);
        *(s16x4*)&x_lds[e * 148 + seg * 4] = pk;
    }
    __syncthreads();   // x, sh visible

    // ---- per-lane state: lane owns edge eLoc ----
    const int eLoc = wv * 16 + n;
    const unsigned short* xr = &x_lds[eLoc * 148];
    const float sh0 = sh_lds[eLoc * 4 + 0];
    const float s1x = sh_lds[eLoc * 4 + 1];
    const float s1y = sh_lds[eLoc * 4 + 2];
    const float s1z = sh_lds[eLoc * 4 + 3];

    const unsigned short* hp = &h_lds[eLoc * 72];
    s16x8 h0 = *(const s16x8*)&hp[quad * 8];          // B[k=quad*8+j][n=edge]
    s16x8 h1 = *(const s16x8*)&hp[32 + quad * 8];

    float Y0e[4][2] = {};
    float Y1o[4][3] = {};
    float Y1e[4][3] = {};
    float Y0o[4]    = {};

    const int scol = tid >> 2, sseg = tid & 3;

    // prefetch chunk 0 of W2T
    s16x8 g0, g1;
    {
        const unsigned short* gp = w2t + (size_t)scol * 64 + sseg * 16;
        g0 = *(const s16x8*)gp;
        g1 = *(const s16x8*)(gp + 8);
    }

#define DO_MFMA(t)                                                          \
    const unsigned short* bp = buf + ((t) * 16 + n) * 72;                   \
    s16x8 aT0 = *(const s16x8*)&bp[quad * 8];                               \
    s16x8 aT1 = *(const s16x8*)&bp[32 + quad * 8];                          \
    f32x4 acc;                                                              \
    acc[0] = bvv[t].x; acc[1] = bvv[t].y; acc[2] = bvv[t].z; acc[3] = bvv[t].w; \
    acc = __builtin_amdgcn_mfma_f32_16x16x32_bf16(aT0, h0, acc, 0, 0, 0);   \
    acc = __builtin_amdgcn_mfma_f32_16x16x32_bf16(aT1, h1, acc, 0, 0, 0);

    for (int c = 0; c < 53; ++c) {
        unsigned short* buf = (c & 1) ? wd1 : wd0;
        *(s16x8*)&buf[scol * 72 + sseg * 16]     = g0;
        *(s16x8*)&buf[scol * 72 + sseg * 16 + 8] = g1;
        const int c0 = c * 64;
        float4 bvv[4];
#pragma unroll
        for (int t = 0; t < 4; ++t)
            bvv[t] = *(const float4*)(b2s + c0 + 16 * t + quad * 4);
        __syncthreads();
        if (c < 52) {
            const unsigned short* gp = w2t + (size_t)(c + 1) * 4096 + (size_t)scol * 64 + sseg * 16;
            g0 = *(const s16x8*)gp;
            g1 = *(const s16x8*)(gp + 8);
        }

        if (c < 24) {                                        // ---- 0e: col = i*32 + out
            float ov = 0.f;
#pragma unroll
            for (int t = 0; t < 4; ++t) {
                DO_MFMA(t)
                if ((t & 1) == 0) {
                    int i = 2 * c + (t >> 1);
                    if (c < 16) ov = b2f(xr[i]) * sh0;
                    else {
                        int ib = 32 + 3 * (i - 32);
                        ov = b2f(xr[ib]) * s1x + b2f(xr[ib + 1]) * s1y + b2f(xr[ib + 2]) * s1z;
                    }
                }
                const int kk = t & 1;
                Y0e[0][kk] += ov * acc[0];
                Y0e[1][kk] += ov * acc[1];
                Y0e[2][kk] += ov * acc[2];
                Y0e[3][kk] += ov * acc[3];
            }
        } else if (c < 40) {                                 // ---- 1o: col = 1536 + i*16 + out
#pragma unroll
            for (int t = 0; t < 4; ++t) {
                DO_MFMA(t)
                int i = 4 * (c - 24) + t;
                float o0, o1, o2;
                if (c < 32) {                                // i<32: x0e[i] * sh1
                    float xv = b2f(xr[i]);
                    o0 = xv * s1x; o1 = xv * s1y; o2 = xv * s1z;
                } else if (c < 36) {                         // 32<=i<48: x1o[i-32] * sh0
                    int ib = 32 + 3 * (i - 32);
                    o0 = b2f(xr[ib]) * sh0; o1 = b2f(xr[ib + 1]) * sh0; o2 = b2f(xr[ib + 2]) * sh0;
                } else {                                     // i>=48: cross(x1e[i-48], sh1)
                    int ib = 80 + 3 * (i - 48);
                    float a0v = b2f(xr[ib]), a1v = b2f(xr[ib + 1]), a2v = b2f(xr[ib + 2]);
                    o0 = a1v * s1z - a2v * s1y;
                    o1 = a2v * s1x - a0v * s1z;
                    o2 = a0v * s1y - a1v * s1x;
                }
#pragma unroll
                for (int r = 0; r < 4; ++r) {
                    float w = acc[r];
                    Y1o[r][0] += o0 * w; Y1o[r][1] += o1 * w; Y1o[r][2] += o2 * w;
                }
            }
        } else if (c < 50) {                                 // ---- 1e: col = 2560 + i*16 + out
#pragma unroll
            for (int t = 0; t < 4; ++t) {
                DO_MFMA(t)
                int i = 4 * (c - 40) + t;
                float o0, o1, o2;
                if (c < 44) {                                // i<16: cross(x1o[i], sh1)
                    int ib = 32 + 3 * i;
                    float a0v = b2f(xr[ib]), a1v = b2f(xr[ib + 1]), a2v = b2f(xr[ib + 2]);
                    o0 = a1v * s1z - a2v * s1y;
                    o1 = a2v * s1x - a0v * s1z;
                    o2 = a0v * s1y - a1v * s1x;
                } else if (c < 48) {                         // 16<=i<32: x1e[i-16] * sh0
                    int ib = 80 + 3 * (i - 16);
                    o0 = b2f(xr[ib]) * sh0; o1 = b2f(xr[ib + 1]) * sh0; o2 = b2f(xr[ib + 2]) * sh0;
                } else {                                     // i>=32: x0o[i-32] * sh1
                    float xv = b2f(xr[128 + (i - 32)]);
                    o0 = xv * s1x; o1 = xv * s1y; o2 = xv * s1z;
                }
#pragma unroll
                for (int r = 0; r < 4; ++r) {
                    float w = acc[r];
                    Y1e[r][0] += o0 * w; Y1e[r][1] += o1 * w; Y1e[r][2] += o2 * w;
                }
            }
        } else {                                             // ---- 0o: col = 3200 + i*8 + out
#pragma unroll
            for (int t = 0; t < 4; ++t) {
                DO_MFMA(t)
                float ov;
                if (c < 52) {                                // i<16: dot(x1e[i], sh1)
                    int i = 8 * (c - 50) + 2 * t + (quad >> 1);
                    int ib = 80 + 3 * i;
                    ov = b2f(xr[ib]) * s1x + b2f(xr[ib + 1]) * s1y + b2f(xr[ib + 2]) * s1z;
                } else {                                     // i>=16: x0o[i-16] * sh0
                    int i2 = 2 * t + (quad >> 1);
                    ov = b2f(xr[128 + i2]) * sh0;
                }
                Y0o[0] += ov * acc[0];
                Y0o[1] += ov * acc[1];
                Y0o[2] += ov * acc[2];
                Y0o[3] += ov * acc[3];
            }
        }
    }
#undef DO_MFMA

    // ---- stage Y rows in LDS (reuse x + W2 dbuf region), then coalesced atomics ----
    __syncthreads();                          // everyone done reading x / dbuf
    float* stage = (float*)smem;              // 64 rows x 144 f32
    {
        float* srow = stage + eLoc * 144;
#pragma unroll
        for (int r = 0; r < 4; ++r) {
            int qr = quad * 4 + r;
            srow[qr]            = Y0e[r][0];
            srow[16 + qr]       = Y0e[r][1];
            srow[32 + qr * 3 + 0] = Y1o[r][0];
            srow[32 + qr * 3 + 1] = Y1o[r][1];
            srow[32 + qr * 3 + 2] = Y1o[r][2];
            srow[80 + qr * 3 + 0] = Y1e[r][0];
            srow[80 + qr * 3 + 1] = Y1e[r][1];
            srow[80 + qr * 3 + 2] = Y1e[r][2];
            srow[128 + (quad & 1) * 4 + r + (quad >> 1) * 8] = Y0o[r];
        }
    }
    __syncthreads();
    // wave wv scatters its own 16 edges, lanes cover consecutive features (coalesced)
    for (int j = 0; j < 16; ++j) {
        int e = wv * 16 + j;
        float* dp = acc_g + (size_t)src_lds[e] * FEAT;
        const float* sr = stage + e * 144;
        atomicAdd(dp + lane,      sr[lane]);
        atomicAdd(dp + 64 + lane, sr[64 + lane]);
        if (lane < 8)
            atomicAdd(dp + 128 + lane, sr[128 + lane] + sr[136 + lane]);
    }
}

// ---------------- finalize: mean + residual (fp32 out) ----------------
__global__ void finalize_kernel(const float* __restrict__ acc_g,
                                const float* __restrict__ cnt_g,
                                const float* __restrict__ node_attr,
                                float* __restrict__ out) {
    int idx = blockIdx.x * 256 + threadIdx.x;
    if (idx >= N_NODES * FEAT) return;
    int nn = idx / FEAT;
    float c = cnt_g[nn];
    out[idx] = acc_g[idx] / fmaxf(c, 1.0f) + node_attr[idx];
}

extern "C" void kernel_launch(void* const* d_in, const int* in_sizes, int n_in,
                              void* d_out, int out_size, void* d_ws, size_t ws_size,
                              hipStream_t stream) {
    const float* node_attr  = (const float*)d_in[0];
    const int*   edge_index = (const int*)d_in[1];
    const float* edge_attr  = (const float*)d_in[2];
    const float* edge_sh    = (const float*)d_in[3];
    const float* fc_w1      = (const float*)d_in[4];
    const float* fc_b1      = (const float*)d_in[5];
    const float* fc_w2      = (const float*)d_in[6];
    const float* fc_b2      = (const float*)d_in[7];
    float* out = (float*)d_out;

    char* ws = (char*)d_ws;
    float* acc_g = (float*)ws;                                      // 8192*136*4 = 4456448
    float* cnt_g = (float*)(ws + 4456448);                          // 32768
    unsigned short* w2t = (unsigned short*)(ws + 4489216);          // 434176
    unsigned short* w1t = (unsigned short*)(ws + 4489216 + 434176); // 8192
    float* b2s = (float*)(ws + 4489216 + 434176 + 8192);            // 13568

    hipMemsetAsync(ws, 0, 4489216, stream);  // zero acc + cnt
    transpose_kernel<<<54, 256, 0, stream>>>(fc_w2, fc_w1, fc_b2, w2t, w1t, b2s);
    tpconv_main<<<1024, 256, 0, stream>>>(node_attr, edge_index, edge_attr, edge_sh,
                                          w1t, fc_b1, w2t, b2s, acc_g, cnt_g);
    finalize_kernel<<<(N_NODES * FEAT + 255) / 256, 256, 0, stream>>>(acc_g, cnt_g, node_attr, out);
}